// Round 1
// baseline (960.820 us; speedup 1.0000x reference)
//
#include <hip/hip_runtime.h>
#include <math.h>

#define B_   256
#define S_   500
#define QD_  128
#define M_   64
#define VD_  256

// ---------------------------------------------------------------------------
// Transpose key_mem [64][128] into quad layout kTq[k4*64 + m] = float4 of
// key_mem[m][4k4..4k4+3], so attn kernel's per-lane reads are coalesced.
// ---------------------------------------------------------------------------
__global__ void kT_kernel(const float* __restrict__ key_mem, float4* __restrict__ kTq)
{
    int i = blockIdx.x * 256 + threadIdx.x;
    if (i < 32 * 64) {
        int m  = i & 63;
        int k4 = i >> 6;
        kTq[i] = *reinterpret_cast<const float4*>(&key_mem[m * QD_ + k4 * 4]);
    }
}

// ---------------------------------------------------------------------------
// Kernel A: w_all[row][m] = softmax_m( q_emb[row] . key_mem[m] )
// rows are r = b*Tcur + tc  (global t = t0 + tc)
// block = 256 threads = 4 waves; each wave handles 4 rows; lane m = slot.
// ---------------------------------------------------------------------------
__global__ __launch_bounds__(256) void attn_kernel(
    const int*    __restrict__ q_data,
    const float*  __restrict__ q_embed_w,
    const float4* __restrict__ kTq,
    float*        __restrict__ w_out,
    int Tcur, int t0)
{
    __shared__ int    qidx[16];
    __shared__ float4 q4[16][32];

    const int tid = threadIdx.x;
    const int r0  = blockIdx.x * 16;

    if (tid < 16) {
        int r  = r0 + tid;
        int b  = r / Tcur;
        int tc = r - b * Tcur;
        qidx[tid] = q_data[b * S_ + t0 + tc];
    }
    __syncthreads();
    for (int i = tid; i < 512; i += 256) {
        int row = i >> 5, k4 = i & 31;
        q4[row][k4] = *reinterpret_cast<const float4*>(
            &q_embed_w[(size_t)qidx[row] * QD_ + k4 * 4]);
    }
    __syncthreads();

    const int wave = tid >> 6, lane = tid & 63;
    const int rr = wave * 4;

    float s0 = 0.f, s1 = 0.f, s2 = 0.f, s3 = 0.f;
    for (int k4 = 0; k4 < 32; ++k4) {
        float4 kv = kTq[k4 * 64 + lane];
        float4 a0 = q4[rr + 0][k4];
        float4 a1 = q4[rr + 1][k4];
        float4 a2 = q4[rr + 2][k4];
        float4 a3 = q4[rr + 3][k4];
        s0 = fmaf(a0.x, kv.x, s0); s0 = fmaf(a0.y, kv.y, s0);
        s0 = fmaf(a0.z, kv.z, s0); s0 = fmaf(a0.w, kv.w, s0);
        s1 = fmaf(a1.x, kv.x, s1); s1 = fmaf(a1.y, kv.y, s1);
        s1 = fmaf(a1.z, kv.z, s1); s1 = fmaf(a1.w, kv.w, s1);
        s2 = fmaf(a2.x, kv.x, s2); s2 = fmaf(a2.y, kv.y, s2);
        s2 = fmaf(a2.z, kv.z, s2); s2 = fmaf(a2.w, kv.w, s2);
        s3 = fmaf(a3.x, kv.x, s3); s3 = fmaf(a3.y, kv.y, s3);
        s3 = fmaf(a3.z, kv.z, s3); s3 = fmaf(a3.w, kv.w, s3);
    }

    // per-row softmax across the 64 lanes
    float s[4] = { s0, s1, s2, s3 };
    #pragma unroll
    for (int j = 0; j < 4; ++j) {
        float mx = s[j];
        #pragma unroll
        for (int off = 32; off; off >>= 1) mx = fmaxf(mx, __shfl_xor(mx, off));
        float e = __expf(s[j] - mx);
        float sum = e;
        #pragma unroll
        for (int off = 32; off; off >>= 1) sum += __shfl_xor(sum, off);
        float w = e / sum;
        w_out[(size_t)(r0 + rr + j) * 64 + lane] = w;
    }
}

// ---------------------------------------------------------------------------
// Kernel B: erase_all = sigmoid(qa_emb @ We + be); add_all = tanh(qa_emb @ Wa + ba)
// block = 512 threads: threads 0..255 -> erase column c, 256..511 -> add column c.
// 16 rows per block; per-thread 16-row register accumulation; W reads coalesced.
// ---------------------------------------------------------------------------
__global__ __launch_bounds__(512) void ea_kernel(
    const int*   __restrict__ qa_data,
    const float* __restrict__ qa_embed_w,
    const float* __restrict__ erase_W,
    const float* __restrict__ erase_b,
    const float* __restrict__ add_W,
    const float* __restrict__ add_b,
    float*       __restrict__ erase_out,
    float*       __restrict__ add_out,
    int Tcur, int t0)
{
    __shared__ int    qidx[16];
    __shared__ float4 qa4[16][32];

    const int tid = threadIdx.x;
    const int r0  = blockIdx.x * 16;

    if (tid < 16) {
        int r  = r0 + tid;
        int b  = r / Tcur;
        int tc = r - b * Tcur;
        qidx[tid] = qa_data[b * S_ + t0 + tc];
    }
    __syncthreads();
    {
        int row = tid >> 5, k4 = tid & 31;   // 512 threads == 16*32 quads
        qa4[row][k4] = *reinterpret_cast<const float4*>(
            &qa_embed_w[(size_t)qidx[row] * QD_ + k4 * 4]);
    }
    __syncthreads();

    const int  c   = tid & 255;
    const bool isE = tid < 256;
    const float* Wp = isE ? erase_W : add_W;

    float acc[16];
    #pragma unroll
    for (int r = 0; r < 16; ++r) acc[r] = 0.f;

    for (int k4 = 0; k4 < 32; ++k4) {
        float w0 = Wp[(size_t)(k4 * 4 + 0) * 256 + c];
        float w1 = Wp[(size_t)(k4 * 4 + 1) * 256 + c];
        float w2 = Wp[(size_t)(k4 * 4 + 2) * 256 + c];
        float w3 = Wp[(size_t)(k4 * 4 + 3) * 256 + c];
        #pragma unroll
        for (int r = 0; r < 16; ++r) {
            float4 qv = qa4[r][k4];
            acc[r] = fmaf(qv.x, w0, acc[r]);
            acc[r] = fmaf(qv.y, w1, acc[r]);
            acc[r] = fmaf(qv.z, w2, acc[r]);
            acc[r] = fmaf(qv.w, w3, acc[r]);
        }
    }

    const float bias = isE ? erase_b[c] : add_b[c];
    float* outp = isE ? erase_out : add_out;
    #pragma unroll
    for (int r = 0; r < 16; ++r) {
        float x = acc[r] + bias;
        float y;
        if (isE) {
            y = 1.f / (1.f + __expf(-x));
        } else {
            float t  = __expf(-2.f * fabsf(x));     // stable tanh
            float ta = (1.f - t) / (1.f + t);
            y = (x < 0.f) ? -ta : ta;
        }
        outp[(size_t)(r0 + r) * 256 + c] = y;
    }
}

// ---------------------------------------------------------------------------
// Scan kernel: one block per batch element b, 256 threads, thread d owns
// column Mv[:,d] in 64 VGPRs. Sequential over tc; w staged 16 steps into LDS;
// erase/add prefetched one step ahead.
// ---------------------------------------------------------------------------
__global__ __launch_bounds__(256) void scan_kernel(
    const int*   __restrict__ q_data,
    const float* __restrict__ init_mv,
    const float* __restrict__ w_c,
    const float* __restrict__ e_c,
    const float* __restrict__ a_c,
    float*       __restrict__ out,
    float*       __restrict__ state,
    int Tcur, int t0, int last)
{
    const int b = blockIdx.x;
    const int d = threadIdx.x;

    __shared__ float w_lds[16 * 64];
    __shared__ int   qrow[S_];

    for (int i = d; i < S_; i += 256) qrow[i] = q_data[b * S_ + i];

    float mv[64];
    if (t0 == 0) {
        #pragma unroll
        for (int m = 0; m < 64; ++m) mv[m] = init_mv[m * VD_ + d];
        out[(size_t)b * S_ * VD_ + d] = 0.f;     // out[:,0,:] = 0
    } else {
        #pragma unroll
        for (int m = 0; m < 64; ++m) mv[m] = state[((size_t)b * 64 + m) * VD_ + d];
    }

    const size_t rbase = (size_t)b * Tcur;
    float ecur = e_c[rbase * VD_ + d];
    float acur = a_c[rbase * VD_ + d];

    for (int tc = 0; tc < Tcur; ++tc) {
        if ((tc & 15) == 0) {
            __syncthreads();
            int nw = (Tcur - tc < 16 ? Tcur - tc : 16) * 64;
            for (int i = d; i < nw; i += 256)
                w_lds[i] = w_c[(rbase + tc) * 64 + i];
            __syncthreads();
        }

        float enx = 0.f, anx = 0.f;
        if (tc + 1 < Tcur) {
            enx = e_c[(rbase + tc + 1) * VD_ + d];
            anx = a_c[(rbase + tc + 1) * VD_ + d];
        }

        const int  t  = t0 + tc;
        const bool wr = qrow[t] >= 1;
        const int  wo = (tc & 15) * 64;
        float rd = 0.f;

        if (wr) {
            #pragma unroll
            for (int m4 = 0; m4 < 16; ++m4) {
                float4 wq = *reinterpret_cast<const float4*>(&w_lds[wo + m4 * 4]);
                {
                    float v = mv[m4 * 4 + 0];
                    rd = fmaf(wq.x, v, rd);
                    mv[m4 * 4 + 0] = fmaf(wq.x, fmaf(-ecur, v, acur), v);
                }
                {
                    float v = mv[m4 * 4 + 1];
                    rd = fmaf(wq.y, v, rd);
                    mv[m4 * 4 + 1] = fmaf(wq.y, fmaf(-ecur, v, acur), v);
                }
                {
                    float v = mv[m4 * 4 + 2];
                    rd = fmaf(wq.z, v, rd);
                    mv[m4 * 4 + 2] = fmaf(wq.z, fmaf(-ecur, v, acur), v);
                }
                {
                    float v = mv[m4 * 4 + 3];
                    rd = fmaf(wq.w, v, rd);
                    mv[m4 * 4 + 3] = fmaf(wq.w, fmaf(-ecur, v, acur), v);
                }
            }
        } else {
            #pragma unroll
            for (int m4 = 0; m4 < 16; ++m4) {
                float4 wq = *reinterpret_cast<const float4*>(&w_lds[wo + m4 * 4]);
                rd = fmaf(wq.x, mv[m4 * 4 + 0], rd);
                rd = fmaf(wq.y, mv[m4 * 4 + 1], rd);
                rd = fmaf(wq.z, mv[m4 * 4 + 2], rd);
                rd = fmaf(wq.w, mv[m4 * 4 + 3], rd);
            }
        }

        if (t + 1 < S_)
            out[((size_t)b * S_ + (t + 1)) * VD_ + d] = rd;

        ecur = enx;
        acur = anx;
    }

    if (!last) {
        #pragma unroll
        for (int m = 0; m < 64; ++m)
            state[((size_t)b * 64 + m) * VD_ + d] = mv[m];
    }
}

// ---------------------------------------------------------------------------
extern "C" void kernel_launch(void* const* d_in, const int* in_sizes, int n_in,
                              void* d_out, int out_size, void* d_ws, size_t ws_size,
                              hipStream_t stream)
{
    const int*   q_data  = (const int*)  d_in[0];
    const int*   qa_data = (const int*)  d_in[1];
    const float* q_emb   = (const float*)d_in[2];
    const float* qa_emb  = (const float*)d_in[3];
    const float* key_mem = (const float*)d_in[4];
    const float* init_mv = (const float*)d_in[5];
    const float* erase_W = (const float*)d_in[6];
    const float* erase_b = (const float*)d_in[7];
    const float* add_W   = (const float*)d_in[8];
    const float* add_b   = (const float*)d_in[9];
    float* out = (float*)d_out;

    char* ws = (char*)d_ws;
    float4* kTq = (float4*)ws;
    size_t off = (size_t)2048 * sizeof(float4);              // 32 KB
    float* state = (float*)(ws + off);
    off += (size_t)B_ * 64 * VD_ * sizeof(float);            // 16.78 MB

    const size_t per_step = (size_t)B_ * (64 + VD_ + VD_) * sizeof(float); // 589824 B
    size_t avail = ws_size > off ? ws_size - off : 0;
    int Tc = (int)(avail / per_step);
    if (Tc > S_) Tc = S_;
    if (Tc < 1)  Tc = 1;

    kT_kernel<<<dim3(8), dim3(256), 0, stream>>>(key_mem, kTq);

    for (int t0 = 0; t0 < S_; t0 += Tc) {
        int Tcur = (S_ - t0 < Tc) ? (S_ - t0) : Tc;
        float* w_c = (float*)(ws + off);
        float* e_c = w_c + (size_t)B_ * Tcur * 64;
        float* a_c = e_c + (size_t)B_ * Tcur * VD_;
        int nrows = B_ * Tcur;                                // multiple of 16 (B_=256)
        int last  = (t0 + Tcur >= S_) ? 1 : 0;

        attn_kernel<<<dim3(nrows / 16), dim3(256), 0, stream>>>(
            q_data, q_emb, kTq, w_c, Tcur, t0);
        ea_kernel<<<dim3(nrows / 16), dim3(512), 0, stream>>>(
            qa_data, qa_emb, erase_W, erase_b, add_W, add_b, e_c, a_c, Tcur, t0);
        scan_kernel<<<dim3(B_), dim3(256), 0, stream>>>(
            q_data, init_mv, w_c, e_c, a_c, out, state, Tcur, t0, last);
    }
}

// Round 2
// 687.052 us; speedup vs baseline: 1.3985x; 1.3985x over previous
//
#include <hip/hip_runtime.h>
#include <math.h>

#define B_   256
#define S_   500
#define QD_  128
#define M_   64
#define VD_  256
#define CH_  16

// ---------------------------------------------------------------------------
// Transpose key_mem [64][128] into quad layout kTq[k4*64 + m] = float4 of
// key_mem[m][4k4..4k4+3], so attn kernel's per-lane reads are coalesced.
// ---------------------------------------------------------------------------
__global__ void kT_kernel(const float* __restrict__ key_mem, float4* __restrict__ kTq)
{
    int i = blockIdx.x * 256 + threadIdx.x;
    if (i < 32 * 64) {
        int m  = i & 63;
        int k4 = i >> 6;
        kTq[i] = *reinterpret_cast<const float4*>(&key_mem[m * QD_ + k4 * 4]);
    }
}

// ---------------------------------------------------------------------------
// Kernel A: w_all[row][m] = softmax_m( q_emb[row] . key_mem[m] )
// ---------------------------------------------------------------------------
__global__ __launch_bounds__(256) void attn_kernel(
    const int*    __restrict__ q_data,
    const float*  __restrict__ q_embed_w,
    const float4* __restrict__ kTq,
    float*        __restrict__ w_out,
    int Tcur, int t0)
{
    __shared__ int    qidx[16];
    __shared__ float4 q4[16][32];

    const int tid = threadIdx.x;
    const int r0  = blockIdx.x * 16;

    if (tid < 16) {
        int r  = r0 + tid;
        int b  = r / Tcur;
        int tc = r - b * Tcur;
        qidx[tid] = q_data[b * S_ + t0 + tc];
    }
    __syncthreads();
    for (int i = tid; i < 512; i += 256) {
        int row = i >> 5, k4 = i & 31;
        q4[row][k4] = *reinterpret_cast<const float4*>(
            &q_embed_w[(size_t)qidx[row] * QD_ + k4 * 4]);
    }
    __syncthreads();

    const int wave = tid >> 6, lane = tid & 63;
    const int rr = wave * 4;

    float s0 = 0.f, s1 = 0.f, s2 = 0.f, s3 = 0.f;
    for (int k4 = 0; k4 < 32; ++k4) {
        float4 kv = kTq[k4 * 64 + lane];
        float4 a0 = q4[rr + 0][k4];
        float4 a1 = q4[rr + 1][k4];
        float4 a2 = q4[rr + 2][k4];
        float4 a3 = q4[rr + 3][k4];
        s0 = fmaf(a0.x, kv.x, s0); s0 = fmaf(a0.y, kv.y, s0);
        s0 = fmaf(a0.z, kv.z, s0); s0 = fmaf(a0.w, kv.w, s0);
        s1 = fmaf(a1.x, kv.x, s1); s1 = fmaf(a1.y, kv.y, s1);
        s1 = fmaf(a1.z, kv.z, s1); s1 = fmaf(a1.w, kv.w, s1);
        s2 = fmaf(a2.x, kv.x, s2); s2 = fmaf(a2.y, kv.y, s2);
        s2 = fmaf(a2.z, kv.z, s2); s2 = fmaf(a2.w, kv.w, s2);
        s3 = fmaf(a3.x, kv.x, s3); s3 = fmaf(a3.y, kv.y, s3);
        s3 = fmaf(a3.z, kv.z, s3); s3 = fmaf(a3.w, kv.w, s3);
    }

    float s[4] = { s0, s1, s2, s3 };
    #pragma unroll
    for (int j = 0; j < 4; ++j) {
        float mx = s[j];
        #pragma unroll
        for (int off = 32; off; off >>= 1) mx = fmaxf(mx, __shfl_xor(mx, off));
        float e = __expf(s[j] - mx);
        float sum = e;
        #pragma unroll
        for (int off = 32; off; off >>= 1) sum += __shfl_xor(sum, off);
        float w = e / sum;
        w_out[(size_t)(r0 + rr + j) * 64 + lane] = w;
    }
}

// ---------------------------------------------------------------------------
// Kernel B: erase_all = sigmoid(qa_emb @ We + be); add_all = tanh(qa_emb @ Wa + ba)
// ---------------------------------------------------------------------------
__global__ __launch_bounds__(512) void ea_kernel(
    const int*   __restrict__ qa_data,
    const float* __restrict__ qa_embed_w,
    const float* __restrict__ erase_W,
    const float* __restrict__ erase_b,
    const float* __restrict__ add_W,
    const float* __restrict__ add_b,
    float*       __restrict__ erase_out,
    float*       __restrict__ add_out,
    int Tcur, int t0)
{
    __shared__ int    qidx[16];
    __shared__ float4 qa4[16][32];

    const int tid = threadIdx.x;
    const int r0  = blockIdx.x * 16;

    if (tid < 16) {
        int r  = r0 + tid;
        int b  = r / Tcur;
        int tc = r - b * Tcur;
        qidx[tid] = qa_data[b * S_ + t0 + tc];
    }
    __syncthreads();
    {
        int row = tid >> 5, k4 = tid & 31;
        qa4[row][k4] = *reinterpret_cast<const float4*>(
            &qa_embed_w[(size_t)qidx[row] * QD_ + k4 * 4]);
    }
    __syncthreads();

    const int  c   = tid & 255;
    const bool isE = tid < 256;
    const float* Wp = isE ? erase_W : add_W;

    float acc[16];
    #pragma unroll
    for (int r = 0; r < 16; ++r) acc[r] = 0.f;

    for (int k4 = 0; k4 < 32; ++k4) {
        float w0 = Wp[(size_t)(k4 * 4 + 0) * 256 + c];
        float w1 = Wp[(size_t)(k4 * 4 + 1) * 256 + c];
        float w2 = Wp[(size_t)(k4 * 4 + 2) * 256 + c];
        float w3 = Wp[(size_t)(k4 * 4 + 3) * 256 + c];
        #pragma unroll
        for (int r = 0; r < 16; ++r) {
            float4 qv = qa4[r][k4];
            acc[r] = fmaf(qv.x, w0, acc[r]);
            acc[r] = fmaf(qv.y, w1, acc[r]);
            acc[r] = fmaf(qv.z, w2, acc[r]);
            acc[r] = fmaf(qv.w, w3, acc[r]);
        }
    }

    const float bias = isE ? erase_b[c] : add_b[c];
    float* outp = isE ? erase_out : add_out;
    #pragma unroll
    for (int r = 0; r < 16; ++r) {
        float x = acc[r] + bias;
        float y;
        if (isE) {
            y = 1.f / (1.f + __expf(-x));
        } else {
            float t  = __expf(-2.f * fabsf(x));
            float ta = (1.f - t) / (1.f + t);
            y = (x < 0.f) ? -ta : ta;
        }
        outp[(size_t)(r0 + r) * 256 + c] = y;
    }
}

// ---------------------------------------------------------------------------
// Scan: one block per batch, thread d owns Mv[:,d] in 16 float4 VGPRs.
// w/e/a staged in double-buffered LDS chunks of CH_ steps; next chunk's
// global loads issued before compute, ds_written after (T14 split).
// ---------------------------------------------------------------------------
__device__ __forceinline__ void scan_step(
    float4 (&mv)[16], const float* wrow, float ec, float ac, bool wr, float& rd)
{
    const float em = wr ? ec : 0.f;
    const float am = wr ? ac : 0.f;
    float rd0 = 0.f, rd1 = 0.f, rd2 = 0.f, rd3 = 0.f;
    #pragma unroll
    for (int m4 = 0; m4 < 16; ++m4) {
        float4 wq = *reinterpret_cast<const float4*>(wrow + m4 * 4);
        float4 v  = mv[m4];
        rd0 = fmaf(wq.x, v.x, rd0);
        rd1 = fmaf(wq.y, v.y, rd1);
        rd2 = fmaf(wq.z, v.z, rd2);
        rd3 = fmaf(wq.w, v.w, rd3);
        mv[m4].x = fmaf(wq.x, fmaf(-em, v.x, am), v.x);
        mv[m4].y = fmaf(wq.y, fmaf(-em, v.y, am), v.y);
        mv[m4].z = fmaf(wq.z, fmaf(-em, v.z, am), v.z);
        mv[m4].w = fmaf(wq.w, fmaf(-em, v.w, am), v.w);
    }
    rd = (rd0 + rd1) + (rd2 + rd3);
}

__global__ __launch_bounds__(256, 1) void scan_kernel(
    const int*   __restrict__ q_data,
    const float* __restrict__ init_mv,
    const float* __restrict__ w_c,
    const float* __restrict__ e_c,
    const float* __restrict__ a_c,
    float*       __restrict__ out,
    float*       __restrict__ state,
    int Tcur, int t0, int last)
{
    __shared__ float w_lds[2][CH_ * 64];
    __shared__ float e_lds[2][CH_ * VD_];
    __shared__ float a_lds[2][CH_ * VD_];
    __shared__ int   qrow[S_];

    const int b = blockIdx.x;
    const int d = threadIdx.x;

    for (int i = d; i < S_; i += 256) qrow[i] = q_data[b * S_ + i];

    float4 mv[16];
    if (t0 == 0) {
        #pragma unroll
        for (int m4 = 0; m4 < 16; ++m4) {
            mv[m4].x = init_mv[(m4 * 4 + 0) * VD_ + d];
            mv[m4].y = init_mv[(m4 * 4 + 1) * VD_ + d];
            mv[m4].z = init_mv[(m4 * 4 + 2) * VD_ + d];
            mv[m4].w = init_mv[(m4 * 4 + 3) * VD_ + d];
        }
        out[(size_t)b * S_ * VD_ + d] = 0.f;
    } else {
        #pragma unroll
        for (int m4 = 0; m4 < 16; ++m4) {
            mv[m4].x = state[((size_t)b * 64 + m4 * 4 + 0) * VD_ + d];
            mv[m4].y = state[((size_t)b * 64 + m4 * 4 + 1) * VD_ + d];
            mv[m4].z = state[((size_t)b * 64 + m4 * 4 + 2) * VD_ + d];
            mv[m4].w = state[((size_t)b * 64 + m4 * 4 + 3) * VD_ + d];
        }
    }

    const size_t rbase = (size_t)b * Tcur;
    const int nch = (Tcur + CH_ - 1) / CH_;

    {
        int tc0 = Tcur < CH_ ? Tcur : CH_;
        int nw4 = tc0 * 16, ne4 = tc0 * 64;
        if (d < nw4)
            *reinterpret_cast<float4*>(&w_lds[0][d * 4]) =
                *reinterpret_cast<const float4*>(&w_c[rbase * 64 + (size_t)d * 4]);
        #pragma unroll
        for (int j = 0; j < 4; ++j) {
            int idx = d + 256 * j;
            if (idx < ne4) {
                *reinterpret_cast<float4*>(&e_lds[0][idx * 4]) =
                    *reinterpret_cast<const float4*>(&e_c[rbase * VD_ + (size_t)idx * 4]);
                *reinterpret_cast<float4*>(&a_lds[0][idx * 4]) =
                    *reinterpret_cast<const float4*>(&a_c[rbase * VD_ + (size_t)idx * 4]);
            }
        }
    }
    __syncthreads();

    for (int c = 0; c < nch; ++c) {
        const int  tb   = c * CH_;
        const int  tcnt = (Tcur - tb < CH_) ? (Tcur - tb) : CH_;
        const int  buf  = c & 1;
        const bool hn   = (c + 1 < nch);
        const int  tnn  = hn ? ((Tcur - tb - CH_ < CH_) ? Tcur - tb - CH_ : CH_) : 0;
        const int  nw4n = tnn * 16, ne4n = tnn * 64;

        float4 rw, re0, re1, re2, re3, ra0, ra1, ra2, ra3;
        if (hn) {
            const size_t wb = (rbase + tb + CH_) * 64;
            const size_t eb = (rbase + tb + CH_) * (size_t)VD_;
            if (d < nw4n)
                rw = *reinterpret_cast<const float4*>(&w_c[wb + (size_t)d * 4]);
            if (d < ne4n) {
                re0 = *reinterpret_cast<const float4*>(&e_c[eb + (size_t)d * 4]);
                ra0 = *reinterpret_cast<const float4*>(&a_c[eb + (size_t)d * 4]);
            }
            if (d + 256 < ne4n) {
                re1 = *reinterpret_cast<const float4*>(&e_c[eb + (size_t)(d + 256) * 4]);
                ra1 = *reinterpret_cast<const float4*>(&a_c[eb + (size_t)(d + 256) * 4]);
            }
            if (d + 512 < ne4n) {
                re2 = *reinterpret_cast<const float4*>(&e_c[eb + (size_t)(d + 512) * 4]);
                ra2 = *reinterpret_cast<const float4*>(&a_c[eb + (size_t)(d + 512) * 4]);
            }
            if (d + 768 < ne4n) {
                re3 = *reinterpret_cast<const float4*>(&e_c[eb + (size_t)(d + 768) * 4]);
                ra3 = *reinterpret_cast<const float4*>(&a_c[eb + (size_t)(d + 768) * 4]);
            }
        }

        const float* wbuf = w_lds[buf];
        const float* ebuf = e_lds[buf];
        const float* abuf = a_lds[buf];
        float* outp = &out[((size_t)b * S_ + (t0 + tb + 1)) * VD_ + d];

        if (tcnt == CH_) {
            #pragma unroll
            for (int tt = 0; tt < CH_; ++tt) {
                const int  t  = t0 + tb + tt;
                const bool wr = qrow[t] >= 1;
                float rd;
                scan_step(mv, wbuf + tt * 64, ebuf[tt * VD_ + d], abuf[tt * VD_ + d], wr, rd);
                if (t + 1 < S_) outp[(size_t)tt * VD_] = rd;
            }
        } else {
            for (int tt = 0; tt < tcnt; ++tt) {
                const int  t  = t0 + tb + tt;
                const bool wr = qrow[t] >= 1;
                float rd;
                scan_step(mv, wbuf + tt * 64, ebuf[tt * VD_ + d], abuf[tt * VD_ + d], wr, rd);
                if (t + 1 < S_) outp[(size_t)tt * VD_] = rd;
            }
        }

        if (hn) {
            if (d < nw4n)
                *reinterpret_cast<float4*>(&w_lds[buf ^ 1][d * 4]) = rw;
            if (d < ne4n) {
                *reinterpret_cast<float4*>(&e_lds[buf ^ 1][d * 4]) = re0;
                *reinterpret_cast<float4*>(&a_lds[buf ^ 1][d * 4]) = ra0;
            }
            if (d + 256 < ne4n) {
                *reinterpret_cast<float4*>(&e_lds[buf ^ 1][(d + 256) * 4]) = re1;
                *reinterpret_cast<float4*>(&a_lds[buf ^ 1][(d + 256) * 4]) = ra1;
            }
            if (d + 512 < ne4n) {
                *reinterpret_cast<float4*>(&e_lds[buf ^ 1][(d + 512) * 4]) = re2;
                *reinterpret_cast<float4*>(&a_lds[buf ^ 1][(d + 512) * 4]) = ra2;
            }
            if (d + 768 < ne4n) {
                *reinterpret_cast<float4*>(&e_lds[buf ^ 1][(d + 768) * 4]) = re3;
                *reinterpret_cast<float4*>(&a_lds[buf ^ 1][(d + 768) * 4]) = ra3;
            }
        }
        __syncthreads();
    }

    if (!last) {
        #pragma unroll
        for (int m4 = 0; m4 < 16; ++m4) {
            state[((size_t)b * 64 + m4 * 4 + 0) * VD_ + d] = mv[m4].x;
            state[((size_t)b * 64 + m4 * 4 + 1) * VD_ + d] = mv[m4].y;
            state[((size_t)b * 64 + m4 * 4 + 2) * VD_ + d] = mv[m4].z;
            state[((size_t)b * 64 + m4 * 4 + 3) * VD_ + d] = mv[m4].w;
        }
    }
}

// ---------------------------------------------------------------------------
extern "C" void kernel_launch(void* const* d_in, const int* in_sizes, int n_in,
                              void* d_out, int out_size, void* d_ws, size_t ws_size,
                              hipStream_t stream)
{
    const int*   q_data  = (const int*)  d_in[0];
    const int*   qa_data = (const int*)  d_in[1];
    const float* q_emb   = (const float*)d_in[2];
    const float* qa_emb  = (const float*)d_in[3];
    const float* key_mem = (const float*)d_in[4];
    const float* init_mv = (const float*)d_in[5];
    const float* erase_W = (const float*)d_in[6];
    const float* erase_b = (const float*)d_in[7];
    const float* add_W   = (const float*)d_in[8];
    const float* add_b   = (const float*)d_in[9];
    float* out = (float*)d_out;

    char* ws = (char*)d_ws;
    float4* kTq = (float4*)ws;
    size_t off = (size_t)2048 * sizeof(float4);              // 32 KB
    float* state = (float*)(ws + off);
    off += (size_t)B_ * 64 * VD_ * sizeof(float);            // 16.78 MB

    const size_t per_step = (size_t)B_ * (64 + VD_ + VD_) * sizeof(float);
    size_t avail = ws_size > off ? ws_size - off : 0;
    int Tc = (int)(avail / per_step);
    if (Tc > S_) Tc = S_;
    if (Tc < 1)  Tc = 1;

    kT_kernel<<<dim3(8), dim3(256), 0, stream>>>(key_mem, kTq);

    for (int t0 = 0; t0 < S_; t0 += Tc) {
        int Tcur = (S_ - t0 < Tc) ? (S_ - t0) : Tc;
        float* w_c = (float*)(ws + off);
        float* e_c = w_c + (size_t)B_ * Tcur * 64;
        float* a_c = e_c + (size_t)B_ * Tcur * VD_;
        int nrows = B_ * Tcur;
        int last  = (t0 + Tcur >= S_) ? 1 : 0;

        attn_kernel<<<dim3(nrows / 16), dim3(256), 0, stream>>>(
            q_data, q_emb, kTq, w_c, Tcur, t0);
        ea_kernel<<<dim3(nrows / 16), dim3(512), 0, stream>>>(
            qa_data, qa_emb, erase_W, erase_b, add_W, add_b, e_c, a_c, Tcur, t0);
        scan_kernel<<<dim3(B_), dim3(256), 0, stream>>>(
            q_data, init_mv, w_c, e_c, a_c, out, state, Tcur, t0, last);
    }
}

// Round 3
// 427.424 us; speedup vs baseline: 2.2479x; 1.6074x over previous
//
#include <hip/hip_runtime.h>
#include <math.h>

#define B_     256
#define S_     500
#define QD_    128
#define M_     64
#define VD_    256
#define CH_    16
#define NQ_    10000          // q indices in [0, 10000]
#define NQA_   20000          // qa indices in [0, 20000]
#define WROWS  (NQ_ + 1)
#define EAROWS (NQA_ + 1)

// ---------------------------------------------------------------------------
// Transpose key_mem [64][128] into quad layout kTq[k4*64 + m] = float4 of
// key_mem[m][4k4..4k4+3], so wtab kernel's per-lane reads are coalesced.
// ---------------------------------------------------------------------------
__global__ void kT_kernel(const float* __restrict__ key_mem, float4* __restrict__ kTq)
{
    int i = blockIdx.x * 256 + threadIdx.x;
    if (i < 32 * 64) {
        int m  = i & 63;
        int k4 = i >> 6;
        kTq[i] = *reinterpret_cast<const float4*>(&key_mem[m * QD_ + k4 * 4]);
    }
}

// ---------------------------------------------------------------------------
// wtab[r][m] = softmax_m( q_embed_w[r] . key_mem[m] ),  r in [0, WROWS)
// 16 rows per block; wave handles 4 rows; lane = memory slot.
// ---------------------------------------------------------------------------
__global__ __launch_bounds__(256) void wtab_kernel(
    const float*  __restrict__ q_embed_w,
    const float4* __restrict__ kTq,
    float*        __restrict__ wtab)
{
    __shared__ float4 q4[16][32];

    const int tid = threadIdx.x;
    const int r0  = blockIdx.x * 16;

    for (int i = tid; i < 512; i += 256) {
        int row = i >> 5, k4 = i & 31;
        int r   = r0 + row; if (r > NQ_) r = NQ_;
        q4[row][k4] = *reinterpret_cast<const float4*>(
            &q_embed_w[(size_t)r * QD_ + k4 * 4]);
    }
    __syncthreads();

    const int wave = tid >> 6, lane = tid & 63;
    const int rr = wave * 4;

    float s0 = 0.f, s1 = 0.f, s2 = 0.f, s3 = 0.f;
    for (int k4 = 0; k4 < 32; ++k4) {
        float4 kv = kTq[k4 * 64 + lane];
        float4 a0 = q4[rr + 0][k4];
        float4 a1 = q4[rr + 1][k4];
        float4 a2 = q4[rr + 2][k4];
        float4 a3 = q4[rr + 3][k4];
        s0 = fmaf(a0.x, kv.x, s0); s0 = fmaf(a0.y, kv.y, s0);
        s0 = fmaf(a0.z, kv.z, s0); s0 = fmaf(a0.w, kv.w, s0);
        s1 = fmaf(a1.x, kv.x, s1); s1 = fmaf(a1.y, kv.y, s1);
        s1 = fmaf(a1.z, kv.z, s1); s1 = fmaf(a1.w, kv.w, s1);
        s2 = fmaf(a2.x, kv.x, s2); s2 = fmaf(a2.y, kv.y, s2);
        s2 = fmaf(a2.z, kv.z, s2); s2 = fmaf(a2.w, kv.w, s2);
        s3 = fmaf(a3.x, kv.x, s3); s3 = fmaf(a3.y, kv.y, s3);
        s3 = fmaf(a3.z, kv.z, s3); s3 = fmaf(a3.w, kv.w, s3);
    }

    float s[4] = { s0, s1, s2, s3 };
    #pragma unroll
    for (int j = 0; j < 4; ++j) {
        float mx = s[j];
        #pragma unroll
        for (int off = 32; off; off >>= 1) mx = fmaxf(mx, __shfl_xor(mx, off));
        float e = __expf(s[j] - mx);
        float sum = e;
        #pragma unroll
        for (int off = 32; off; off >>= 1) sum += __shfl_xor(sum, off);
        if (r0 + rr + j < WROWS)
            wtab[(size_t)(r0 + rr + j) * 64 + lane] = e / sum;
    }
}

// ---------------------------------------------------------------------------
// eatab[r][0..255]   = sigmoid(qa_embed_w[r] @ erase_W + erase_b)
// eatab[r][256..511] = tanh   (qa_embed_w[r] @ add_W   + add_b)
// 16 rows per block, 512 threads (tid<256 -> erase col, else add col).
// ---------------------------------------------------------------------------
__global__ __launch_bounds__(512) void eatab_kernel(
    const float* __restrict__ qa_embed_w,
    const float* __restrict__ erase_W,
    const float* __restrict__ erase_b,
    const float* __restrict__ add_W,
    const float* __restrict__ add_b,
    float*       __restrict__ eatab)
{
    __shared__ float4 qa4[16][32];

    const int tid = threadIdx.x;
    const int r0  = blockIdx.x * 16;

    {
        int row = tid >> 5, k4 = tid & 31;
        int r   = r0 + row; if (r > NQA_) r = NQA_;
        qa4[row][k4] = *reinterpret_cast<const float4*>(
            &qa_embed_w[(size_t)r * QD_ + k4 * 4]);
    }
    __syncthreads();

    const int  c   = tid & 255;
    const bool isE = tid < 256;
    const float* Wp = isE ? erase_W : add_W;

    float acc[16];
    #pragma unroll
    for (int r = 0; r < 16; ++r) acc[r] = 0.f;

    for (int k4 = 0; k4 < 32; ++k4) {
        float w0 = Wp[(size_t)(k4 * 4 + 0) * 256 + c];
        float w1 = Wp[(size_t)(k4 * 4 + 1) * 256 + c];
        float w2 = Wp[(size_t)(k4 * 4 + 2) * 256 + c];
        float w3 = Wp[(size_t)(k4 * 4 + 3) * 256 + c];
        #pragma unroll
        for (int r = 0; r < 16; ++r) {
            float4 qv = qa4[r][k4];
            acc[r] = fmaf(qv.x, w0, acc[r]);
            acc[r] = fmaf(qv.y, w1, acc[r]);
            acc[r] = fmaf(qv.z, w2, acc[r]);
            acc[r] = fmaf(qv.w, w3, acc[r]);
        }
    }

    const float bias = isE ? erase_b[c] : add_b[c];
    #pragma unroll
    for (int r = 0; r < 16; ++r) {
        float x = acc[r] + bias;
        float y;
        if (isE) {
            y = 1.f / (1.f + __expf(-x));
        } else {
            float t  = __expf(-2.f * fabsf(x));
            float ta = (1.f - t) / (1.f + t);
            y = (x < 0.f) ? -ta : ta;
        }
        if (r0 + r < EAROWS)
            eatab[(size_t)(r0 + r) * 512 + tid] = y;
    }
}

// ---------------------------------------------------------------------------
// Scan: one block per batch, thread d owns Mv[:,d] in 16 float4 VGPRs.
// Per CH_-step chunk, gather w rows (wtab) and erase/add rows (eatab) by
// embedding index into double-buffered LDS; issue next chunk's gathers early,
// commit to LDS late (T14 split). Single dispatch covers all S_ steps.
// ---------------------------------------------------------------------------
__device__ __forceinline__ void scan_step(
    float4 (&mv)[16], const float* wrow, float ec, float ac, bool wr, float& rd)
{
    const float em = wr ? ec : 0.f;
    const float am = wr ? ac : 0.f;
    float rd0 = 0.f, rd1 = 0.f, rd2 = 0.f, rd3 = 0.f;
    #pragma unroll
    for (int m4 = 0; m4 < 16; ++m4) {
        float4 wq = *reinterpret_cast<const float4*>(wrow + m4 * 4);
        float4 v  = mv[m4];
        rd0 = fmaf(wq.x, v.x, rd0);
        rd1 = fmaf(wq.y, v.y, rd1);
        rd2 = fmaf(wq.z, v.z, rd2);
        rd3 = fmaf(wq.w, v.w, rd3);
        mv[m4].x = fmaf(wq.x, fmaf(-em, v.x, am), v.x);
        mv[m4].y = fmaf(wq.y, fmaf(-em, v.y, am), v.y);
        mv[m4].z = fmaf(wq.z, fmaf(-em, v.z, am), v.z);
        mv[m4].w = fmaf(wq.w, fmaf(-em, v.w, am), v.w);
    }
    rd = (rd0 + rd1) + (rd2 + rd3);
}

__global__ __launch_bounds__(256, 1) void scan_kernel(
    const int*   __restrict__ q_data,
    const int*   __restrict__ qa_data,
    const float* __restrict__ init_mv,
    const float* __restrict__ wtab,
    const float* __restrict__ eatab,
    float*       __restrict__ out)
{
    __shared__ float w_lds[2][CH_ * 64];
    __shared__ float e_lds[2][CH_ * VD_];
    __shared__ float a_lds[2][CH_ * VD_];
    __shared__ int   qrow[S_];
    __shared__ int   qarow[S_];

    const int b = blockIdx.x;
    const int d = threadIdx.x;

    for (int i = d; i < S_; i += 256) {
        qrow[i]  = q_data[b * S_ + i];
        qarow[i] = qa_data[b * S_ + i];
    }
    __syncthreads();

    float4 mv[16];
    #pragma unroll
    for (int m4 = 0; m4 < 16; ++m4) {
        mv[m4].x = init_mv[(m4 * 4 + 0) * VD_ + d];
        mv[m4].y = init_mv[(m4 * 4 + 1) * VD_ + d];
        mv[m4].z = init_mv[(m4 * 4 + 2) * VD_ + d];
        mv[m4].w = init_mv[(m4 * 4 + 3) * VD_ + d];
    }
    out[(size_t)b * S_ * VD_ + d] = 0.f;

    const int wstep = d >> 4, wq4 = d & 15;     // w-gather mapping
    const int nch = (S_ + CH_ - 1) / CH_;

    // synchronous gather of chunk 0
    {
        *reinterpret_cast<float4*>(&w_lds[0][d * 4]) =
            *reinterpret_cast<const float4*>(&wtab[(size_t)qrow[wstep] * 64 + wq4 * 4]);
        #pragma unroll
        for (int j = 0; j < 4; ++j) {
            int idx = d + 256 * j;
            int st = idx >> 6, qq = idx & 63;
            const float* rowp = &eatab[(size_t)qarow[st] * 512];
            *reinterpret_cast<float4*>(&e_lds[0][idx * 4]) =
                *reinterpret_cast<const float4*>(&rowp[qq * 4]);
            *reinterpret_cast<float4*>(&a_lds[0][idx * 4]) =
                *reinterpret_cast<const float4*>(&rowp[256 + qq * 4]);
        }
    }
    __syncthreads();

    for (int c = 0; c < nch; ++c) {
        const int  tb   = c * CH_;
        const int  tcnt = (S_ - tb < CH_) ? (S_ - tb) : CH_;
        const int  buf  = c & 1;
        const bool hn   = (c + 1 < nch);
        const int  tnn  = hn ? ((S_ - tb - CH_ < CH_) ? S_ - tb - CH_ : CH_) : 0;

        // issue next chunk's gathers (T14: issue-early)
        float4 rw, re[4], ra[4];
        if (hn) {
            if (wstep < tnn)
                rw = *reinterpret_cast<const float4*>(
                    &wtab[(size_t)qrow[tb + CH_ + wstep] * 64 + wq4 * 4]);
            #pragma unroll
            for (int j = 0; j < 4; ++j) {
                int idx = d + 256 * j;
                int st = idx >> 6, qq = idx & 63;
                if (st < tnn) {
                    const float* rowp = &eatab[(size_t)qarow[tb + CH_ + st] * 512];
                    re[j] = *reinterpret_cast<const float4*>(&rowp[qq * 4]);
                    ra[j] = *reinterpret_cast<const float4*>(&rowp[256 + qq * 4]);
                }
            }
        }

        const float* wbuf = w_lds[buf];
        const float* ebuf = e_lds[buf];
        const float* abuf = a_lds[buf];
        float* outp = &out[((size_t)b * S_ + (tb + 1)) * VD_ + d];

        if (tcnt == CH_) {
            #pragma unroll
            for (int tt = 0; tt < CH_; ++tt) {
                const int  t  = tb + tt;
                const bool wr = qrow[t] >= 1;
                float rd;
                scan_step(mv, wbuf + tt * 64, ebuf[tt * VD_ + d], abuf[tt * VD_ + d], wr, rd);
                if (t + 1 < S_) outp[(size_t)tt * VD_] = rd;
            }
        } else {
            for (int tt = 0; tt < tcnt; ++tt) {
                const int  t  = tb + tt;
                const bool wr = qrow[t] >= 1;
                float rd;
                scan_step(mv, wbuf + tt * 64, ebuf[tt * VD_ + d], abuf[tt * VD_ + d], wr, rd);
                if (t + 1 < S_) outp[(size_t)tt * VD_] = rd;
            }
        }

        // write-late: commit staged gathers to the other buffer
        if (hn) {
            if (wstep < tnn)
                *reinterpret_cast<float4*>(&w_lds[buf ^ 1][d * 4]) = rw;
            #pragma unroll
            for (int j = 0; j < 4; ++j) {
                int idx = d + 256 * j;
                int st = idx >> 6;
                if (st < tnn) {
                    *reinterpret_cast<float4*>(&e_lds[buf ^ 1][idx * 4]) = re[j];
                    *reinterpret_cast<float4*>(&a_lds[buf ^ 1][idx * 4]) = ra[j];
                }
            }
        }
        __syncthreads();
    }
}

// ---------------------------------------------------------------------------
extern "C" void kernel_launch(void* const* d_in, const int* in_sizes, int n_in,
                              void* d_out, int out_size, void* d_ws, size_t ws_size,
                              hipStream_t stream)
{
    const int*   q_data  = (const int*)  d_in[0];
    const int*   qa_data = (const int*)  d_in[1];
    const float* q_emb   = (const float*)d_in[2];
    const float* qa_emb  = (const float*)d_in[3];
    const float* key_mem = (const float*)d_in[4];
    const float* init_mv = (const float*)d_in[5];
    const float* erase_W = (const float*)d_in[6];
    const float* erase_b = (const float*)d_in[7];
    const float* add_W   = (const float*)d_in[8];
    const float* add_b   = (const float*)d_in[9];
    float* out = (float*)d_out;

    char* ws = (char*)d_ws;
    float4* kTq = (float4*)ws;
    size_t off = (size_t)2048 * sizeof(float4);               // 32 KB
    float* wtab = (float*)(ws + off);
    off += (size_t)WROWS * 64 * sizeof(float);                // 2.56 MB
    off = (off + 255) & ~(size_t)255;
    float* eatab = (float*)(ws + off);
    off += (size_t)EAROWS * 512 * sizeof(float);              // 40.96 MB

    kT_kernel<<<dim3(8), dim3(256), 0, stream>>>(key_mem, kTq);
    wtab_kernel<<<dim3((WROWS + 15) / 16), dim3(256), 0, stream>>>(
        q_emb, kTq, wtab);
    eatab_kernel<<<dim3((EAROWS + 15) / 16), dim3(512), 0, stream>>>(
        qa_emb, erase_W, erase_b, add_W, add_b, eatab);
    scan_kernel<<<dim3(B_), dim3(256), 0, stream>>>(
        q_data, qa_data, init_mv, wtab, eatab, out);
}

// Round 4
// 296.887 us; speedup vs baseline: 3.2363x; 1.4397x over previous
//
#include <hip/hip_runtime.h>
#include <math.h>

#define B_     256
#define S_     500
#define QD_    128
#define M_     64
#define VD_    256
#define CH_    16
#define NQ_    10000          // q indices in [0, 10000]
#define NQA_   20000          // qa indices in [0, 20000]
#define WROWS  (NQ_ + 1)
#define EAROWS (NQA_ + 1)

// ---------------------------------------------------------------------------
// Transpose key_mem [64][128] into quad layout kTq[k4*64 + m] = float4 of
// key_mem[m][4k4..4k4+3], so wtab kernel's per-lane reads are coalesced.
// ---------------------------------------------------------------------------
__global__ void kT_kernel(const float* __restrict__ key_mem, float4* __restrict__ kTq)
{
    int i = blockIdx.x * 256 + threadIdx.x;
    if (i < 32 * 64) {
        int m  = i & 63;
        int k4 = i >> 6;
        kTq[i] = *reinterpret_cast<const float4*>(&key_mem[m * QD_ + k4 * 4]);
    }
}

// ---------------------------------------------------------------------------
// wtab[r][m] = softmax_m( q_embed_w[r] . key_mem[m] ),  r in [0, WROWS)
// ---------------------------------------------------------------------------
__global__ __launch_bounds__(256) void wtab_kernel(
    const float*  __restrict__ q_embed_w,
    const float4* __restrict__ kTq,
    float*        __restrict__ wtab)
{
    __shared__ float4 q4[16][32];

    const int tid = threadIdx.x;
    const int r0  = blockIdx.x * 16;

    for (int i = tid; i < 512; i += 256) {
        int row = i >> 5, k4 = i & 31;
        int r   = r0 + row; if (r > NQ_) r = NQ_;
        q4[row][k4] = *reinterpret_cast<const float4*>(
            &q_embed_w[(size_t)r * QD_ + k4 * 4]);
    }
    __syncthreads();

    const int wave = tid >> 6, lane = tid & 63;
    const int rr = wave * 4;

    float s0 = 0.f, s1 = 0.f, s2 = 0.f, s3 = 0.f;
    for (int k4 = 0; k4 < 32; ++k4) {
        float4 kv = kTq[k4 * 64 + lane];
        float4 a0 = q4[rr + 0][k4];
        float4 a1 = q4[rr + 1][k4];
        float4 a2 = q4[rr + 2][k4];
        float4 a3 = q4[rr + 3][k4];
        s0 = fmaf(a0.x, kv.x, s0); s0 = fmaf(a0.y, kv.y, s0);
        s0 = fmaf(a0.z, kv.z, s0); s0 = fmaf(a0.w, kv.w, s0);
        s1 = fmaf(a1.x, kv.x, s1); s1 = fmaf(a1.y, kv.y, s1);
        s1 = fmaf(a1.z, kv.z, s1); s1 = fmaf(a1.w, kv.w, s1);
        s2 = fmaf(a2.x, kv.x, s2); s2 = fmaf(a2.y, kv.y, s2);
        s2 = fmaf(a2.z, kv.z, s2); s2 = fmaf(a2.w, kv.w, s2);
        s3 = fmaf(a3.x, kv.x, s3); s3 = fmaf(a3.y, kv.y, s3);
        s3 = fmaf(a3.z, kv.z, s3); s3 = fmaf(a3.w, kv.w, s3);
    }

    float s[4] = { s0, s1, s2, s3 };
    #pragma unroll
    for (int j = 0; j < 4; ++j) {
        float mx = s[j];
        #pragma unroll
        for (int off = 32; off; off >>= 1) mx = fmaxf(mx, __shfl_xor(mx, off));
        float e = __expf(s[j] - mx);
        float sum = e;
        #pragma unroll
        for (int off = 32; off; off >>= 1) sum += __shfl_xor(sum, off);
        if (r0 + rr + j < WROWS)
            wtab[(size_t)(r0 + rr + j) * 64 + lane] = e / sum;
    }
}

// ---------------------------------------------------------------------------
// eatab[r][0..255]   = sigmoid(qa_embed_w[r] @ erase_W + erase_b)
// eatab[r][256..511] = tanh   (qa_embed_w[r] @ add_W   + add_b)
// ---------------------------------------------------------------------------
__global__ __launch_bounds__(512) void eatab_kernel(
    const float* __restrict__ qa_embed_w,
    const float* __restrict__ erase_W,
    const float* __restrict__ erase_b,
    const float* __restrict__ add_W,
    const float* __restrict__ add_b,
    float*       __restrict__ eatab)
{
    __shared__ float4 qa4[16][32];

    const int tid = threadIdx.x;
    const int r0  = blockIdx.x * 16;

    {
        int row = tid >> 5, k4 = tid & 31;
        int r   = r0 + row; if (r > NQA_) r = NQA_;
        qa4[row][k4] = *reinterpret_cast<const float4*>(
            &qa_embed_w[(size_t)r * QD_ + k4 * 4]);
    }
    __syncthreads();

    const int  c   = tid & 255;
    const bool isE = tid < 256;
    const float* Wp = isE ? erase_W : add_W;

    float acc[16];
    #pragma unroll
    for (int r = 0; r < 16; ++r) acc[r] = 0.f;

    for (int k4 = 0; k4 < 32; ++k4) {
        float w0 = Wp[(size_t)(k4 * 4 + 0) * 256 + c];
        float w1 = Wp[(size_t)(k4 * 4 + 1) * 256 + c];
        float w2 = Wp[(size_t)(k4 * 4 + 2) * 256 + c];
        float w3 = Wp[(size_t)(k4 * 4 + 3) * 256 + c];
        #pragma unroll
        for (int r = 0; r < 16; ++r) {
            float4 qv = qa4[r][k4];
            acc[r] = fmaf(qv.x, w0, acc[r]);
            acc[r] = fmaf(qv.y, w1, acc[r]);
            acc[r] = fmaf(qv.z, w2, acc[r]);
            acc[r] = fmaf(qv.w, w3, acc[r]);
        }
    }

    const float bias = isE ? erase_b[c] : add_b[c];
    #pragma unroll
    for (int r = 0; r < 16; ++r) {
        float x = acc[r] + bias;
        float y;
        if (isE) {
            y = 1.f / (1.f + __expf(-x));
        } else {
            float t  = __expf(-2.f * fabsf(x));
            float ta = (1.f - t) / (1.f + t);
            y = (x < 0.f) ? -ta : ta;
        }
        if (r0 + r < EAROWS)
            eatab[(size_t)(r0 + r) * 512 + tid] = y;
    }
}

// ---------------------------------------------------------------------------
// Scan: one block per batch, 512 threads (8 waves = 2/SIMD).
// Thread tid owns column col = tid>>1 and m-half mo = (tid&1)*32:
// 8 float4 of Mv state in VGPRs. Per step: 8 broadcast ds_read_b128 (w),
// 96 FMAs, one __shfl_xor(1) to combine the two m-half partial reads.
// w double-buffered in LDS (8KB); e/a prefetched straight global->VGPR
// per 16-step chunk (statically indexed register arrays, T14 split).
// ---------------------------------------------------------------------------
__global__ __launch_bounds__(512, 1) void scan_kernel(
    const int*   __restrict__ q_data,
    const int*   __restrict__ qa_data,
    const float* __restrict__ init_mv,
    const float* __restrict__ wtab,
    const float* __restrict__ eatab,
    float*       __restrict__ out)
{
    __shared__ float w_lds[2][CH_ * 64];
    __shared__ int   qrow[S_];
    __shared__ int   qarow[S_];

    const int b    = blockIdx.x;
    const int tid  = threadIdx.x;
    const int col  = tid >> 1;
    const int half = tid & 1;
    const int mo   = half * 32;

    for (int i = tid; i < S_; i += 512) {
        qrow[i]  = q_data[b * S_ + i];
        qarow[i] = qa_data[b * S_ + i];
    }
    __syncthreads();

    // Mv state: m = mo + q*4 + k, column col
    float4 mv[8];
    #pragma unroll
    for (int q = 0; q < 8; ++q) {
        mv[q].x = init_mv[(mo + q * 4 + 0) * VD_ + col];
        mv[q].y = init_mv[(mo + q * 4 + 1) * VD_ + col];
        mv[q].z = init_mv[(mo + q * 4 + 2) * VD_ + col];
        mv[q].w = init_mv[(mo + q * 4 + 3) * VD_ + col];
    }
    if (!half) out[(size_t)b * S_ * VD_ + col] = 0.f;

    // chunk 0 staging: w -> LDS, e/a -> registers
    if (tid < 256) {
        int wstep = tid >> 4, wq4 = tid & 15;
        *reinterpret_cast<float4*>(&w_lds[0][wstep * 64 + wq4 * 4]) =
            *reinterpret_cast<const float4*>(&wtab[(size_t)qrow[wstep] * 64 + wq4 * 4]);
    }
    float ec[CH_], ac[CH_];
    #pragma unroll
    for (int j = 0; j < CH_; ++j) {
        const float* rowp = &eatab[(size_t)qarow[j] * 512 + col];
        ec[j] = rowp[0];
        ac[j] = rowp[256];
    }
    __syncthreads();

    const int nch = (S_ + CH_ - 1) / CH_;
    for (int c = 0; c < nch; ++c) {
        const int  tb  = c * CH_;
        const int  buf = c & 1;
        const bool hn  = (c + 1 < nch);

        // issue next chunk's loads early (T14)
        float4 rw;
        float  en[CH_], an[CH_];
        if (hn) {
            if (tid < 256) {
                int wstep = tid >> 4, wq4 = tid & 15;
                int st = tb + CH_ + wstep; if (st >= S_) st = S_ - 1;
                rw = *reinterpret_cast<const float4*>(
                    &wtab[(size_t)qrow[st] * 64 + wq4 * 4]);
            }
            #pragma unroll
            for (int j = 0; j < CH_; ++j) {
                int st = tb + CH_ + j; if (st >= S_) st = S_ - 1;
                const float* rowp = &eatab[(size_t)qarow[st] * 512 + col];
                en[j] = rowp[0];
                an[j] = rowp[256];
            }
        }

        // compute CH_ steps from current buffers
        #pragma unroll
        for (int tt = 0; tt < CH_; ++tt) {
            const int t = tb + tt;
            if (t < S_) {
                const bool  wr = qrow[t] >= 1;
                const float em = wr ? ec[tt] : 0.f;
                const float am = wr ? ac[tt] : 0.f;
                const float* wrow = &w_lds[buf][tt * 64 + mo];

                float rd0 = 0.f, rd1 = 0.f, rd2 = 0.f, rd3 = 0.f;
                #pragma unroll
                for (int q = 0; q < 8; ++q) {
                    float4 wq = *reinterpret_cast<const float4*>(wrow + q * 4);
                    float4 v  = mv[q];
                    rd0 = fmaf(wq.x, v.x, rd0);
                    rd1 = fmaf(wq.y, v.y, rd1);
                    rd2 = fmaf(wq.z, v.z, rd2);
                    rd3 = fmaf(wq.w, v.w, rd3);
                    mv[q].x = fmaf(wq.x, fmaf(-em, v.x, am), v.x);
                    mv[q].y = fmaf(wq.y, fmaf(-em, v.y, am), v.y);
                    mv[q].z = fmaf(wq.z, fmaf(-em, v.z, am), v.z);
                    mv[q].w = fmaf(wq.w, fmaf(-em, v.w, am), v.w);
                }
                float rd = (rd0 + rd1) + (rd2 + rd3);
                rd += __shfl_xor(rd, 1);
                if (!half && t + 1 < S_)
                    out[((size_t)b * S_ + t + 1) * VD_ + col] = rd;
            }
        }

        // commit staged data (write-late)
        if (hn) {
            if (tid < 256) {
                int wstep = tid >> 4, wq4 = tid & 15;
                *reinterpret_cast<float4*>(&w_lds[buf ^ 1][wstep * 64 + wq4 * 4]) = rw;
            }
            #pragma unroll
            for (int j = 0; j < CH_; ++j) { ec[j] = en[j]; ac[j] = an[j]; }
        }
        __syncthreads();
    }
}

// ---------------------------------------------------------------------------
extern "C" void kernel_launch(void* const* d_in, const int* in_sizes, int n_in,
                              void* d_out, int out_size, void* d_ws, size_t ws_size,
                              hipStream_t stream)
{
    const int*   q_data  = (const int*)  d_in[0];
    const int*   qa_data = (const int*)  d_in[1];
    const float* q_emb   = (const float*)d_in[2];
    const float* qa_emb  = (const float*)d_in[3];
    const float* key_mem = (const float*)d_in[4];
    const float* init_mv = (const float*)d_in[5];
    const float* erase_W = (const float*)d_in[6];
    const float* erase_b = (const float*)d_in[7];
    const float* add_W   = (const float*)d_in[8];
    const float* add_b   = (const float*)d_in[9];
    float* out = (float*)d_out;

    char* ws = (char*)d_ws;
    float4* kTq = (float4*)ws;
    size_t off = (size_t)2048 * sizeof(float4);               // 32 KB
    float* wtab = (float*)(ws + off);
    off += (size_t)WROWS * 64 * sizeof(float);                // 2.56 MB
    off = (off + 255) & ~(size_t)255;
    float* eatab = (float*)(ws + off);
    off += (size_t)EAROWS * 512 * sizeof(float);              // 40.96 MB

    kT_kernel<<<dim3(8), dim3(256), 0, stream>>>(key_mem, kTq);
    wtab_kernel<<<dim3((WROWS + 15) / 16), dim3(256), 0, stream>>>(
        q_emb, kTq, wtab);
    eatab_kernel<<<dim3((EAROWS + 15) / 16), dim3(512), 0, stream>>>(
        qa_emb, erase_W, erase_b, add_W, add_b, eatab);
    scan_kernel<<<dim3(B_), dim3(512), 0, stream>>>(
        q_data, qa_data, init_mv, wtab, eatab, out);
}